// Round 8
// baseline (210.087 us; speedup 1.0000x reference)
//
#include <hip/hip_runtime.h>
#include <hip/hip_bf16.h>

#define NTOK 8192   // B*S
#define DDIM 1024
#define NEXP 32
#define HDIM 128
#define TOPK 4

typedef __attribute__((ext_vector_type(8))) short bf16x8;
typedef __attribute__((ext_vector_type(4))) float f32x4;

typedef unsigned int uint_g __attribute__((address_space(1)));
typedef unsigned int uint_l __attribute__((address_space(3)));

// async 16B/lane global->LDS; LDS dest = wave-uniform base + lane*16.
__device__ __forceinline__ void async_cp16(const void* g, void* l) {
    __builtin_amdgcn_global_load_lds((const uint_g*)g, (uint_l*)l, 16, 0, 0);
}

__device__ inline unsigned short f2bf(float f) {
    unsigned int u = __builtin_bit_cast(unsigned int, f);
    unsigned int r = (u + 0x7fffu + ((u >> 16) & 1u)) >> 16;   // RNE
    return (unsigned short)r;
}
__device__ inline float bf2f(unsigned short s) {
    unsigned int u = ((unsigned int)s) << 16;
    return __builtin_bit_cast(float, u);
}

// ---------------- Kernel PG: fused gate (blocks 0..511) + prep (blocks 512..4607) ----------
// VERBATIM from R7 (harness-verified).
__global__ __launch_bounds__(256) void prep_gate(
    const float* __restrict__ x, const float* __restrict__ es,
    const float* __restrict__ keys, const float* __restrict__ values,
    unsigned short* __restrict__ Kb, unsigned short* __restrict__ Vb,
    unsigned short* __restrict__ Xb,
    int* __restrict__ cnt, int* __restrict__ tok_list, float* __restrict__ gates)
{
    const int tid = threadIdx.x;

    if (blockIdx.x >= 512) {                 // ---- prep part (no barriers) ----
        int idx = (int)(blockIdx.x - 512) * 256 + tid;
        unsigned short o[8];
        if (idx < NEXP * 128 * 128) {        // keys: (e, k0 [128], n [128])
            int n = idx & 127, k0 = (idx >> 7) & 127, e = idx >> 14;
            const float* s = keys + ((size_t)e * DDIM + k0 * 8) * HDIM + n;
            #pragma unroll
            for (int j = 0; j < 8; ++j) o[j] = f2bf(s[(size_t)j * HDIM]);
            *(uint4*)&Kb[(size_t)idx * 8] = *(uint4*)o;
        } else {                             // values: (e, k0 [16], n [1024])
            idx -= NEXP * 128 * 128;
            int n = idx & 1023, k0 = (idx >> 10) & 15, e = idx >> 14;
            const float* s = values + ((size_t)e * HDIM + k0 * 8) * DDIM + n;
            #pragma unroll
            for (int j = 0; j < 8; ++j) o[j] = f2bf(s[(size_t)j * DDIM]);
            *(uint4*)&Vb[(size_t)idx * 8] = *(uint4*)o;
        }
        return;
    }

    // ---- gate part: 16 tokens, full D=1024, fused x->bf16 emit + top-4 + scatter ----
    const int n0 = (int)blockIdx.x * 16;

    __shared__ float smem[4608];             // staging tiles, reused as Lp each quarter
    __shared__ float Ls[16 * 33];            // final logits
    __shared__ int hist[NEXP];
    __shared__ int bbase[NEXP];
    float* Xt  = smem;                       // [d][tok] stride 36
    float* Est = smem + 64 * 36;             // [d][e]   stride 36
    float* Lp  = smem;                       // [rep 8][tok 16][e 33]

    const int t4  = (tid & 3) * 4;
    const int e4  = ((tid >> 2) & 7) * 4;
    const int rep = tid >> 5;

    const int xr = tid & 15, xc4 = (tid >> 4) * 4;
    const int er = tid & 31, ec8 = (tid >> 5) * 8;

    const int ctok = tid >> 4, cd4 = (tid & 15) * 4;   // x->bf16 emit mapping

    // reduce pairs: (tok, e) and (tok+8, e)
    const int rtok = tid >> 5, re = tid & 31;

    float lsum[2] = {0.f, 0.f};

    if (tid < NEXP) hist[tid] = 0;

    // register preload of chunk dc=0 (x: 1 float4, es: 2 float4 per thread)
    float4 xv  = *(const float4*)&x[(size_t)(n0 + xr) * DDIM + xc4];
    float4 ev0 = *(const float4*)&es[(size_t)er * DDIM + ec8];
    float4 ev1 = *(const float4*)&es[(size_t)er * DDIM + ec8 + 4];

    for (int q = 0; q < 4; ++q) {
        float acc[4][4] = {};

        for (int dci = 0; dci < 4; ++dci) {
            const int dc = q * 256 + dci * 64;
            __syncthreads();                 // prev smem reads (compute / Lp-reduce) done
            {
                Xt[(xc4 + 0) * 36 + xr] = xv.x; Xt[(xc4 + 1) * 36 + xr] = xv.y;
                Xt[(xc4 + 2) * 36 + xr] = xv.z; Xt[(xc4 + 3) * 36 + xr] = xv.w;
                Est[(ec8 + 0) * 36 + er] = ev0.x; Est[(ec8 + 1) * 36 + er] = ev0.y;
                Est[(ec8 + 2) * 36 + er] = ev0.z; Est[(ec8 + 3) * 36 + er] = ev0.w;
                Est[(ec8 + 4) * 36 + er] = ev1.x; Est[(ec8 + 5) * 36 + er] = ev1.y;
                Est[(ec8 + 6) * 36 + er] = ev1.z; Est[(ec8 + 7) * 36 + er] = ev1.w;
            }
            const int nxt = dc + 64;
            if (nxt < DDIM) {                // prefetch next chunk into regs (issued early)
                xv  = *(const float4*)&x[(size_t)(n0 + xr) * DDIM + nxt + xc4];
                ev0 = *(const float4*)&es[(size_t)er * DDIM + nxt + ec8];
                ev1 = *(const float4*)&es[(size_t)er * DDIM + nxt + ec8 + 4];
            }
            __syncthreads();

            // fused: emit this x tile as bf16 (each thread 4 contiguous elems of one row)
            {
                unsigned short o[4];
                #pragma unroll
                for (int j = 0; j < 4; ++j) o[j] = f2bf(Xt[(cd4 + j) * 36 + ctok]);
                *(uint2*)&Xb[(size_t)(n0 + ctok) * DDIM + dc + cd4] = *(uint2*)o;
            }

            #pragma unroll
            for (int s = 0; s < 8; ++s) {
                int d = s * 8 + rep;
                float4 xa4 = *(const float4*)&Xt[d * 36 + t4];
                float4 ea4 = *(const float4*)&Est[d * 36 + e4];
                const float xa[4] = {xa4.x, xa4.y, xa4.z, xa4.w};
                const float ea[4] = {ea4.x, ea4.y, ea4.z, ea4.w};
                #pragma unroll
                for (int i = 0; i < 4; ++i)
                    #pragma unroll
                    for (int j = 0; j < 4; ++j)
                        acc[i][j] = fmaf(xa[i], ea[j], acc[i][j]);
            }
        }

        __syncthreads();                     // Xt/Est reads done; smem -> Lp
        #pragma unroll
        for (int i = 0; i < 4; ++i)
            #pragma unroll
            for (int j = 0; j < 4; ++j)
                Lp[(rep * 16 + t4 + i) * 33 + e4 + j] = acc[i][j];
        __syncthreads();

        #pragma unroll
        for (int h = 0; h < 2; ++h) {        // same reduction order as verified version
            int tok = rtok + h * 8;
            float s = 0.f;
            #pragma unroll
            for (int r = 0; r < 8; ++r) s += Lp[(r * 16 + tok) * 33 + re];
            lsum[h] += s;                    // quarter partials summed in q order
        }
    }

    #pragma unroll
    for (int h = 0; h < 2; ++h) Ls[(rtok + h * 8) * 33 + re] = lsum[h];
    __syncthreads();

    int sel[TOPK]; int lpos[TOPK];
    if (tid < 16) {
        float lg[NEXP];
        #pragma unroll
        for (int e2 = 0; e2 < NEXP; ++e2) lg[e2] = Ls[tid * 33 + e2];
        float sv[TOPK];
        #pragma unroll
        for (int j = 0; j < TOPK; ++j) {
            float bv = -3.0e38f; int bi = 0;
            #pragma unroll
            for (int e2 = 0; e2 < NEXP; ++e2) {
                bool taken = false;
                #pragma unroll
                for (int qq = 0; qq < j; ++qq) taken = taken || (sel[qq] == e2);
                float v = taken ? -3.0e38f : lg[e2];
                if (v > bv) { bv = v; bi = e2; }   // strict >: lowest idx wins ties
            }
            sel[j] = bi; sv[j] = bv;
        }
        #pragma unroll
        for (int j = 0; j < TOPK; ++j) {
            gates[(size_t)(n0 + tid) * TOPK + j] = 1.f / (1.f + expf(-sv[j]));
            lpos[j] = atomicAdd(&hist[sel[j]], 1);
        }
    }
    __syncthreads();
    if (tid < NEXP) bbase[tid] = atomicAdd(&cnt[tid], hist[tid]);
    __syncthreads();
    if (tid < 16) {
        #pragma unroll
        for (int j = 0; j < TOPK; ++j)
            tok_list[(size_t)sel[j] * NTOK + bbase[sel[j]] + lpos[j]] = (n0 + tid) * TOPK + j;
    }
}

// ---------------- Kernel F: fused expert FFN, 32-slot tiles, wide-window dbuf ----------------
// All barriers are full-drain __syncthreads (no counted vmcnt anywhere — R3-R5 lesson).
// Latency fix vs R7: stage for chunk t+2 is issued RIGHT AFTER barrier(t) into the
// buffer whose reads just completed, so the forced vmcnt(0) drain at barrier(t+1)
// happens a full chunk period after issue (R0/R7 drained immediately after issue).
// X never touches LDS: direct global->VGPR fragments (16 rows x 64B segments, L3-hit),
// prefetched one chunk ahead into registers. H fragments hoisted to regs for phase B.
// LDS: KV dbuf 2x16KB + Hs 8.96KB + OSB dbuf 9.2KB + 0.4 = 50.6KB -> 3 blocks/CU.
__global__ __launch_bounds__(256) void ffn_fused(
    const unsigned short* __restrict__ Xb,   // [N][1024] bf16
    const unsigned short* __restrict__ Kb,   // [E][128][128][8]
    const unsigned short* __restrict__ Vb,   // [E][16][1024][8]
    const int* __restrict__ cnt, const int* __restrict__ tok_list,
    const float* __restrict__ gates,
    unsigned short* __restrict__ Ob)         // [N*4][1024] bf16
{
    const int bid = blockIdx.x;
    const int e = bid & 31, tile = bid >> 5;
    const int c = cnt[e], base = tile * 32;
    if (base >= c) return;
    const int nt   = min(32, c - base);
    const int tid  = threadIdx.x, wave = tid >> 6, lane = tid & 63;
    const int lm   = lane & 15, quad = lane >> 4;
    const int r2   = (wave >> 1) * 16;       // 16-row half of the 32-slot tile
    const int c2   = (wave & 1) * 64;        // phase A: 64-col half of 128
    const int cw   = (wave & 1) * 32;        // phase B: 32-col half of 64

    __shared__ __align__(16) unsigned short KV[2][8192];  // 32 KB: K / V chunk double-buffer
    __shared__ __align__(16) unsigned short Hs[32 * 140]; // 8.96 KB (stride 140 -> 16 banks)
    __shared__ __align__(16) unsigned short OSB[2][2304]; // 9.2 KB C-tile bounce (dbuf)
    __shared__ int slot[32]; __shared__ int gtok[32]; __shared__ float gs[32];

    if (tid < 32) {
        if (tid < nt) {
            int v = tok_list[(size_t)e * NTOK + base + tid];
            slot[tid] = v; gtok[tid] = v >> 2; gs[tid] = gates[v];
        } else { slot[tid] = -1; gtok[tid] = 0; gs[tid] = 0.f; }
    }
    __syncthreads();

    const unsigned short* Ke = Kb + (size_t)e * 131072;
    const unsigned short* Ve = Vb + (size_t)e * 131072;
    // direct-to-reg X: lane reads row gtok[r2+lm], k-offset (ks*4+quad)*8 within chunk
    const unsigned short* xp = Xb + (size_t)gtok[r2 + lm] * DDIM + quad * 8;

    auto stageK = [&](int t, int cb) {         // K chunk: 16 x 1KB pieces, 4/wave
        #pragma unroll
        for (int i = 0; i < 4; ++i) {
            int p = wave * 4 + i;
            async_cp16(Ke + ((size_t)(t * 8 + (p >> 1)) * 128 + (p & 1) * 64 + lane) * 8,
                       &KV[cb][p * 512]);
        }
    };
    auto stageV = [&](int cc, int vb) {        // V chunk: 16 x 1KB pieces, 4/wave
        #pragma unroll
        for (int i = 0; i < 4; ++i) {
            int p = wave * 4 + i;
            async_cp16(Ve + ((size_t)p * 1024 + cc * 64 + lane) * 8, &KV[vb][p * 512]);
        }
    };

    // ---------------- phase A: H[32][128] = relu(X_tile @ K_e) * g ----------------
    f32x4 acc[4];
    #pragma unroll
    for (int j = 0; j < 4; ++j) acc[j] = (f32x4){0.f, 0.f, 0.f, 0.f};

    stageK(0, 0);
    stageK(1, 1);
    bf16x8 xc0 = *(const bf16x8*)&xp[0];       // chunk 0 X frags (k0 = quad, quad+4)
    bf16x8 xc1 = *(const bf16x8*)&xp[32];
    __syncthreads();                           // prologue drain (K0, K1, x0)

    for (int t = 0; t < 16; ++t) {
        bf16x8 xn0, xn1;
        if (t < 15) {                          // prefetch next X frags into regs
            xn0 = *(const bf16x8*)&xp[(t + 1) * 64];
            xn1 = *(const bf16x8*)&xp[(t + 1) * 64 + 32];
        }
        const unsigned short* B = KV[t & 1];
        #pragma unroll
        for (int ks = 0; ks < 2; ++ks) {
            int k0 = ks * 4 + quad;
            bf16x8 a0 = ks ? xc1 : xc0;
            #pragma unroll
            for (int tj = 0; tj < 4; ++tj) {
                bf16x8 bb = *(const bf16x8*)&B[(k0 * 128 + c2 + tj * 16 + lm) * 8];
                acc[tj] = __builtin_amdgcn_mfma_f32_16x16x32_bf16(a0, bb, acc[tj], 0, 0, 0);
            }
        }
        __syncthreads();                       // drains K(t+1) (issued a full chunk ago)
        if (t + 2 < 16) stageK(t + 2, t & 1);  // restage the buffer whose reads just completed
        xc0 = xn0; xc1 = xn1;
    }

    // epilogue A: V prefetch first (KV bufs free post-barrier), then relu*gate -> Hs
    stageV(0, 0);
    stageV(1, 1);
    #pragma unroll
    for (int reg = 0; reg < 4; ++reg) {
        int m = r2 + quad * 4 + reg;
        float g = gs[m];
        #pragma unroll
        for (int tj = 0; tj < 4; ++tj)
            Hs[m * 140 + c2 + tj * 16 + lm] = f2bf(fmaxf(acc[tj][reg], 0.f) * g);
    }
    __syncthreads();                           // V0/V1 drained (latency under Hs writes); Hs visible

    // ---------------- phase B: Ob = H @ V_e ----------------
    // hoist H fragments to registers (Hs read once)
    bf16x8 hf[4];
    #pragma unroll
    for (int ks = 0; ks < 4; ++ks)
        hf[ks] = *(const bf16x8*)&Hs[(r2 + lm) * 140 + (ks * 4 + quad) * 8];

    const int om = tid >> 3, oq = tid & 7;     // store mapping: 1 uint4/thread
    const int os = slot[om];

    for (int cc = 0; cc < 16; ++cc) {
        const int p = cc & 1;
        f32x4 acc2[2];
        acc2[0] = (f32x4){0.f, 0.f, 0.f, 0.f};
        acc2[1] = (f32x4){0.f, 0.f, 0.f, 0.f};

        #pragma unroll
        for (int ks = 0; ks < 4; ++ks) {
            int k0 = ks * 4 + quad;
            #pragma unroll
            for (int tj = 0; tj < 2; ++tj) {
                bf16x8 bb = *(const bf16x8*)&KV[p][(k0 * 64 + cw + tj * 16 + lm) * 8];
                acc2[tj] = __builtin_amdgcn_mfma_f32_16x16x32_bf16(hf[ks], bb, acc2[tj], 0, 0, 0);
            }
        }

        // bounce C-tile through double-buffered OSB for coalesced 16B stores
        #pragma unroll
        for (int reg = 0; reg < 4; ++reg) {
            int m = r2 + quad * 4 + reg;
            OSB[p][m * 72 + cw + lm]      = f2bf(acc2[0][reg]);
            OSB[p][m * 72 + cw + 16 + lm] = f2bf(acc2[1][reg]);
        }
        __syncthreads();                       // drains V(cc+1) (issued a full chunk ago),
                                               // prior stores; OSB[p] visible; KV[p] reads done
        if (cc + 2 < 16) stageV(cc + 2, p);    // restage freed buffer (wide window to next drain)

        if (os >= 0) {                         // stores: drained at NEXT barrier (overlapped)
            uint4 v0 = *(const uint4*)&OSB[p][om * 72 + oq * 8];
            *(uint4*)(Ob + (size_t)os * DDIM + cc * 64 + oq * 8) = v0;
        }
    }
}

// ---------------- Kernel R: out[n] = sum_j Ob[4n+j]  (bf16 -> fp32) ----------------
__global__ __launch_bounds__(256) void reduce_out(
    const unsigned short* __restrict__ Ob, float* __restrict__ out)
{
    const int tid = threadIdx.x;
    const int n   = blockIdx.x * 2 + (tid >> 7);
    const int cc  = (tid & 127) * 8;

    float s[8] = {};
    #pragma unroll
    for (int j = 0; j < 4; ++j) {
        uint4 v = *(const uint4*)&Ob[((size_t)n * 4 + j) * DDIM + cc];
        const unsigned int w[4] = {v.x, v.y, v.z, v.w};
        #pragma unroll
        for (int q = 0; q < 4; ++q) {
            s[q * 2 + 0] += bf2f((unsigned short)(w[q] & 0xffff));
            s[q * 2 + 1] += bf2f((unsigned short)(w[q] >> 16));
        }
    }
    float4 o0 = {s[0], s[1], s[2], s[3]};
    float4 o1 = {s[4], s[5], s[6], s[7]};
    *(float4*)&out[(size_t)n * DDIM + cc]     = o0;
    *(float4*)&out[(size_t)n * DDIM + cc + 4] = o1;
}

extern "C" void kernel_launch(void* const* d_in, const int* in_sizes, int n_in,
                              void* d_out, int out_size, void* d_ws, size_t ws_size,
                              hipStream_t stream) {
    const float* x      = (const float*)d_in[0];
    const float* es     = (const float*)d_in[1];
    const float* keys   = (const float*)d_in[2];
    const float* values = (const float*)d_in[3];
    float* out          = (float*)d_out;

    // workspace layout (~101 MB)
    char* w = (char*)d_ws;
    int*   cnt      = (int*)w;               w += 256;
    int*   tok_list = (int*)w;               w += (size_t)NEXP * NTOK * sizeof(int);    // 1 MB
    float* gates    = (float*)w;             w += (size_t)NTOK * TOPK * sizeof(float);  // 128 KB
    unsigned short* Kb = (unsigned short*)w; w += (size_t)NEXP * 128 * 128 * 8 * 2;     // 8 MB
    unsigned short* Vb = (unsigned short*)w; w += (size_t)NEXP * 16 * 1024 * 8 * 2;     // 8 MB
    unsigned short* Xb = (unsigned short*)w; w += (size_t)NTOK * DDIM * 2;              // 16.8 MB
    unsigned short* Ob = (unsigned short*)w;                                            // 67 MB

    hipMemsetAsync(cnt, 0, NEXP * sizeof(int), stream);

    prep_gate<<<512 + 4096, 256, 0, stream>>>(x, es, keys, values, Kb, Vb, Xb,
                                              cnt, tok_list, gates);
    ffn_fused<<<256 * NEXP, 256, 0, stream>>>(Xb, Kb, Vb, cnt, tok_list, gates, Ob);
    reduce_out<<<NTOK / 2, 256, 0, stream>>>(Ob, out);
}

// Round 9
// 186.291 us; speedup vs baseline: 1.1277x; 1.1277x over previous
//
#include <hip/hip_runtime.h>
#include <hip/hip_bf16.h>

#define NTOK 8192   // B*S
#define DDIM 1024
#define NEXP 32
#define HDIM 128
#define TOPK 4

typedef __attribute__((ext_vector_type(8))) short bf16x8;
typedef __attribute__((ext_vector_type(4))) float f32x4;

typedef unsigned int uint_g __attribute__((address_space(1)));
typedef unsigned int uint_l __attribute__((address_space(3)));

// async 16B/lane global->LDS; LDS dest = wave-uniform base + lane*16.
__device__ __forceinline__ void async_cp16(const void* g, void* l) {
    __builtin_amdgcn_global_load_lds((const uint_g*)g, (uint_l*)l, 16, 0, 0);
}

__device__ inline unsigned short f2bf(float f) {
    unsigned int u = __builtin_bit_cast(unsigned int, f);
    unsigned int r = (u + 0x7fffu + ((u >> 16) & 1u)) >> 16;   // RNE
    return (unsigned short)r;
}
__device__ inline float bf2f(unsigned short s) {
    unsigned int u = ((unsigned int)s) << 16;
    return __builtin_bit_cast(float, u);
}

// ---------------- Kernel PG: fused gate (blocks 0..511) + prep (blocks 512..4607) ----------
// VERBATIM from R7 (harness-verified).
__global__ __launch_bounds__(256) void prep_gate(
    const float* __restrict__ x, const float* __restrict__ es,
    const float* __restrict__ keys, const float* __restrict__ values,
    unsigned short* __restrict__ Kb, unsigned short* __restrict__ Vb,
    unsigned short* __restrict__ Xb,
    int* __restrict__ cnt, int* __restrict__ tok_list, float* __restrict__ gates)
{
    const int tid = threadIdx.x;

    if (blockIdx.x >= 512) {                 // ---- prep part (no barriers) ----
        int idx = (int)(blockIdx.x - 512) * 256 + tid;
        unsigned short o[8];
        if (idx < NEXP * 128 * 128) {        // keys: (e, k0 [128], n [128])
            int n = idx & 127, k0 = (idx >> 7) & 127, e = idx >> 14;
            const float* s = keys + ((size_t)e * DDIM + k0 * 8) * HDIM + n;
            #pragma unroll
            for (int j = 0; j < 8; ++j) o[j] = f2bf(s[(size_t)j * HDIM]);
            *(uint4*)&Kb[(size_t)idx * 8] = *(uint4*)o;
        } else {                             // values: (e, k0 [16], n [1024])
            idx -= NEXP * 128 * 128;
            int n = idx & 1023, k0 = (idx >> 10) & 15, e = idx >> 14;
            const float* s = values + ((size_t)e * HDIM + k0 * 8) * DDIM + n;
            #pragma unroll
            for (int j = 0; j < 8; ++j) o[j] = f2bf(s[(size_t)j * DDIM]);
            *(uint4*)&Vb[(size_t)idx * 8] = *(uint4*)o;
        }
        return;
    }

    // ---- gate part: 16 tokens, full D=1024, fused x->bf16 emit + top-4 + scatter ----
    const int n0 = (int)blockIdx.x * 16;

    __shared__ float smem[4608];             // staging tiles, reused as Lp each quarter
    __shared__ float Ls[16 * 33];            // final logits
    __shared__ int hist[NEXP];
    __shared__ int bbase[NEXP];
    float* Xt  = smem;                       // [d][tok] stride 36
    float* Est = smem + 64 * 36;             // [d][e]   stride 36
    float* Lp  = smem;                       // [rep 8][tok 16][e 33]

    const int t4  = (tid & 3) * 4;
    const int e4  = ((tid >> 2) & 7) * 4;
    const int rep = tid >> 5;

    const int xr = tid & 15, xc4 = (tid >> 4) * 4;
    const int er = tid & 31, ec8 = (tid >> 5) * 8;

    const int ctok = tid >> 4, cd4 = (tid & 15) * 4;   // x->bf16 emit mapping

    // reduce pairs: (tok, e) and (tok+8, e)
    const int rtok = tid >> 5, re = tid & 31;

    float lsum[2] = {0.f, 0.f};

    if (tid < NEXP) hist[tid] = 0;

    // register preload of chunk dc=0 (x: 1 float4, es: 2 float4 per thread)
    float4 xv  = *(const float4*)&x[(size_t)(n0 + xr) * DDIM + xc4];
    float4 ev0 = *(const float4*)&es[(size_t)er * DDIM + ec8];
    float4 ev1 = *(const float4*)&es[(size_t)er * DDIM + ec8 + 4];

    for (int q = 0; q < 4; ++q) {
        float acc[4][4] = {};

        for (int dci = 0; dci < 4; ++dci) {
            const int dc = q * 256 + dci * 64;
            __syncthreads();                 // prev smem reads (compute / Lp-reduce) done
            {
                Xt[(xc4 + 0) * 36 + xr] = xv.x; Xt[(xc4 + 1) * 36 + xr] = xv.y;
                Xt[(xc4 + 2) * 36 + xr] = xv.z; Xt[(xc4 + 3) * 36 + xr] = xv.w;
                Est[(ec8 + 0) * 36 + er] = ev0.x; Est[(ec8 + 1) * 36 + er] = ev0.y;
                Est[(ec8 + 2) * 36 + er] = ev0.z; Est[(ec8 + 3) * 36 + er] = ev0.w;
                Est[(ec8 + 4) * 36 + er] = ev1.x; Est[(ec8 + 5) * 36 + er] = ev1.y;
                Est[(ec8 + 6) * 36 + er] = ev1.z; Est[(ec8 + 7) * 36 + er] = ev1.w;
            }
            const int nxt = dc + 64;
            if (nxt < DDIM) {                // prefetch next chunk into regs (issued early)
                xv  = *(const float4*)&x[(size_t)(n0 + xr) * DDIM + nxt + xc4];
                ev0 = *(const float4*)&es[(size_t)er * DDIM + nxt + ec8];
                ev1 = *(const float4*)&es[(size_t)er * DDIM + nxt + ec8 + 4];
            }
            __syncthreads();

            // fused: emit this x tile as bf16 (each thread 4 contiguous elems of one row)
            {
                unsigned short o[4];
                #pragma unroll
                for (int j = 0; j < 4; ++j) o[j] = f2bf(Xt[(cd4 + j) * 36 + ctok]);
                *(uint2*)&Xb[(size_t)(n0 + ctok) * DDIM + dc + cd4] = *(uint2*)o;
            }

            #pragma unroll
            for (int s = 0; s < 8; ++s) {
                int d = s * 8 + rep;
                float4 xa4 = *(const float4*)&Xt[d * 36 + t4];
                float4 ea4 = *(const float4*)&Est[d * 36 + e4];
                const float xa[4] = {xa4.x, xa4.y, xa4.z, xa4.w};
                const float ea[4] = {ea4.x, ea4.y, ea4.z, ea4.w};
                #pragma unroll
                for (int i = 0; i < 4; ++i)
                    #pragma unroll
                    for (int j = 0; j < 4; ++j)
                        acc[i][j] = fmaf(xa[i], ea[j], acc[i][j]);
            }
        }

        __syncthreads();                     // Xt/Est reads done; smem -> Lp
        #pragma unroll
        for (int i = 0; i < 4; ++i)
            #pragma unroll
            for (int j = 0; j < 4; ++j)
                Lp[(rep * 16 + t4 + i) * 33 + e4 + j] = acc[i][j];
        __syncthreads();

        #pragma unroll
        for (int h = 0; h < 2; ++h) {        // same reduction order as verified version
            int tok = rtok + h * 8;
            float s = 0.f;
            #pragma unroll
            for (int r = 0; r < 8; ++r) s += Lp[(r * 16 + tok) * 33 + re];
            lsum[h] += s;                    // quarter partials summed in q order
        }
    }

    #pragma unroll
    for (int h = 0; h < 2; ++h) Ls[(rtok + h * 8) * 33 + re] = lsum[h];
    __syncthreads();

    int sel[TOPK]; int lpos[TOPK];
    if (tid < 16) {
        float lg[NEXP];
        #pragma unroll
        for (int e2 = 0; e2 < NEXP; ++e2) lg[e2] = Ls[tid * 33 + e2];
        float sv[TOPK];
        #pragma unroll
        for (int j = 0; j < TOPK; ++j) {
            float bv = -3.0e38f; int bi = 0;
            #pragma unroll
            for (int e2 = 0; e2 < NEXP; ++e2) {
                bool taken = false;
                #pragma unroll
                for (int qq = 0; qq < j; ++qq) taken = taken || (sel[qq] == e2);
                float v = taken ? -3.0e38f : lg[e2];
                if (v > bv) { bv = v; bi = e2; }   // strict >: lowest idx wins ties
            }
            sel[j] = bi; sv[j] = bv;
        }
        #pragma unroll
        for (int j = 0; j < TOPK; ++j) {
            gates[(size_t)(n0 + tid) * TOPK + j] = 1.f / (1.f + expf(-sv[j]));
            lpos[j] = atomicAdd(&hist[sel[j]], 1);
        }
    }
    __syncthreads();
    if (tid < NEXP) bbase[tid] = atomicAdd(&cnt[tid], hist[tid]);
    __syncthreads();
    if (tid < 16) {
        #pragma unroll
        for (int j = 0; j < TOPK; ++j)
            tok_list[(size_t)sel[j] * NTOK + bbase[sel[j]] + lpos[j]] = (n0 + tid) * TOPK + j;
    }
}

// ---------------- Kernel F: fused expert FFN, 64-slot tiles ----------------
// R0/R6-verified skeleton (2 full-drain barriers per chunk — sync untouched).
// Delta 1 (L2 request rate): X staged 8-lanes-per-row (coalesced 128B/row, line
//   requests per chunk 512 -> 128). Source 16B units XOR-permuted by row&7 so the
//   LINEAR LDS dest (global_load_lds constraint) still yields conflict-free reads
//   (read addr applies the same XOR -> 8 banks, 2 lanes each = free).
// Delta 2: phase-B H fragments hoisted to registers (pattern verified in R2/R7).
__global__ __launch_bounds__(256) void ffn_fused(
    const unsigned short* __restrict__ Xb,   // [N][1024] bf16
    const unsigned short* __restrict__ Kb,   // [E][128][128][8]
    const unsigned short* __restrict__ Vb,   // [E][16][1024][8]
    const int* __restrict__ cnt, const int* __restrict__ tok_list,
    const float* __restrict__ gates,
    unsigned short* __restrict__ Ob)         // [N*4][1024] bf16
{
    const int bid = blockIdx.x;
    const int e = bid & 31, tile = bid >> 5;
    const int c = cnt[e], base = tile * 64;
    if (base >= c) return;
    const int nt   = min(64, c - base);
    const int tid  = threadIdx.x, wave = tid >> 6, lane = tid & 63;
    const int lm   = lane & 15, quad = lane >> 4;
    const int r2   = (wave >> 1) * 32;       // 32-row half of the 64-slot tile
    const int c2   = (wave & 1) * 64;        // phase A: 64-col half of 128
    const int cw   = (wave & 1) * 32;        // phase B: 32-col half of 64

    __shared__ __align__(16) unsigned short KV[8192];     // 16 KB: K[8][128][8] | V[16][64][8]
    __shared__ __align__(16) unsigned short XO[4608];     // 9.2 KB: A: Xs[64][64] | B: OSB[64][72]
    __shared__ __align__(16) unsigned short Hs[64 * 140]; // 17.9 KB (stride 140 -> 16 banks)
    __shared__ int slot[64]; __shared__ int gtok[64]; __shared__ float gs[64];

    if (tid < 64) {
        if (tid < nt) {
            int v = tok_list[(size_t)e * NTOK + base + tid];
            slot[tid] = v; gtok[tid] = v >> 2; gs[tid] = gates[v];
        } else { slot[tid] = -1; gtok[tid] = 0; gs[tid] = 0.f; }
    }
    __syncthreads();

    const unsigned short* Ke = Kb + (size_t)e * 131072;
    const unsigned short* Ve = Vb + (size_t)e * 131072;

    // ---------------- phase A: H[64][128] = X_tile @ K_e ----------------
    f32x4 acc[2][4];
    #pragma unroll
    for (int i = 0; i < 2; ++i)
        #pragma unroll
        for (int j = 0; j < 4; ++j) acc[i][j] = (f32x4){0.f, 0.f, 0.f, 0.f};

    // X staging geometry: piece j covers rows j*8..j*8+7; lane l: row j*8+(l>>3),
    // LDS unit s = l&7; SOURCE unit u = s ^ (row&7)  (involution; read applies same XOR)
    const int xrow = (lane >> 3);            // row-local within a piece
    const int xsub = (lane & 7);
    auto stageA = [&](int t) {
        int dc = t * 64;
        #pragma unroll
        for (int i = 0; i < 4; ++i) {          // K: 16 x 1KB pieces, 4/wave (coalesced)
            int p = wave * 4 + i;
            async_cp16(Ke + ((size_t)(dc / 8 + (p >> 1)) * 128 + (p & 1) * 64 + lane) * 8,
                       &KV[p * 512]);
        }
        #pragma unroll
        for (int i = 0; i < 2; ++i) {          // X: 8 x 1KB pieces, 8 lanes/row, 2/wave
            int j = wave * 2 + i;
            int row = j * 8 + xrow;
            int u = xsub ^ (row & 7);          // pre-swizzled source unit
            async_cp16(Xb + (size_t)gtok[row] * DDIM + dc + u * 8, &XO[j * 512]);
        }
    };

    stageA(0);
    __syncthreads();                           // drain

    const int xx = (quad << 3);                // base k-unit*8 per quad (k0 = ks*4+quad)
    for (int t = 0; t < 16; ++t) {
        #pragma unroll
        for (int ks = 0; ks < 2; ++ks) {
            int k0 = ks * 4 + quad;
            int xo = ((k0 ^ (lm & 7)) & 7) * 8;   // swizzled unit offset (shorts)
            bf16x8 a0 = *(const bf16x8*)&XO[(r2 + lm) * 64 + xo];
            bf16x8 a1 = *(const bf16x8*)&XO[(r2 + 16 + lm) * 64 + xo];
            #pragma unroll
            for (int tj = 0; tj < 4; ++tj) {
                bf16x8 bb = *(const bf16x8*)&KV[(k0 * 128 + c2 + tj * 16 + lm) * 8];
                acc[0][tj] = __builtin_amdgcn_mfma_f32_16x16x32_bf16(a0, bb, acc[0][tj], 0, 0, 0);
                acc[1][tj] = __builtin_amdgcn_mfma_f32_16x16x32_bf16(a1, bb, acc[1][tj], 0, 0, 0);
            }
        }
        if (t < 15) {
            __syncthreads();                   // all reads of chunk t done
            stageA(t + 1);
            __syncthreads();                   // drain chunk t+1
        }
    }
    (void)xx;

    // epilogue A: relu * gate -> Hs (row-major [m][140])
    #pragma unroll
    for (int ti = 0; ti < 2; ++ti)
        #pragma unroll
        for (int reg = 0; reg < 4; ++reg) {
            int m = r2 + ti * 16 + quad * 4 + reg;
            float g = gs[m];
            #pragma unroll
            for (int tj = 0; tj < 4; ++tj)
                Hs[m * 140 + c2 + tj * 16 + lm] = f2bf(fmaxf(acc[ti][tj][reg], 0.f) * g);
        }
    __syncthreads();                           // Hs complete; KV/XO phase-A reads done

    // ---------------- phase B: Ob = H @ V_e ----------------
    auto stageV = [&](int cc) {
        #pragma unroll
        for (int i = 0; i < 4; ++i) {          // V: 16 x 1KB pieces, 4/wave
            int p = wave * 4 + i;
            async_cp16(Ve + ((size_t)p * 1024 + cc * 64 + lane) * 8, &KV[p * 512]);
        }
    };

    stageV(0);

    // hoist H fragments to registers: read Hs once (conflict-free: 140-short stride)
    bf16x8 hf[2][4];                           // [row-half][ks]
    #pragma unroll
    for (int ks = 0; ks < 4; ++ks) {
        hf[0][ks] = *(const bf16x8*)&Hs[(r2 + lm) * 140 + (ks * 4 + quad) * 8];
        hf[1][ks] = *(const bf16x8*)&Hs[(r2 + 16 + lm) * 140 + (ks * 4 + quad) * 8];
    }
    __syncthreads();                           // drain V0 (hoist reads overlapped)

    const int om = tid >> 2, oq = tid & 3;     // store mapping: 2 uint4/thread
    const int os = slot[om];

    for (int cc = 0; cc < 16; ++cc) {
        f32x4 acc2[2][2];
        #pragma unroll
        for (int i = 0; i < 2; ++i) {
            acc2[i][0] = (f32x4){0.f, 0.f, 0.f, 0.f};
            acc2[i][1] = (f32x4){0.f, 0.f, 0.f, 0.f};
        }

        #pragma unroll
        for (int ks = 0; ks < 4; ++ks) {
            int k0 = ks * 4 + quad;
            #pragma unroll
            for (int tj = 0; tj < 2; ++tj) {
                bf16x8 bb = *(const bf16x8*)&KV[(k0 * 64 + cw + tj * 16 + lm) * 8];
                acc2[0][tj] = __builtin_amdgcn_mfma_f32_16x16x32_bf16(hf[0][ks], bb, acc2[0][tj], 0, 0, 0);
                acc2[1][tj] = __builtin_amdgcn_mfma_f32_16x16x32_bf16(hf[1][ks], bb, acc2[1][tj], 0, 0, 0);
            }
        }

        // bounce C-tile through LDS (OSB[64][72]) for coalesced 16B stores
        #pragma unroll
        for (int ti = 0; ti < 2; ++ti)
            #pragma unroll
            for (int reg = 0; reg < 4; ++reg) {
                int m = r2 + ti * 16 + quad * 4 + reg;
                XO[m * 72 + cw + lm]      = f2bf(acc2[ti][0][reg]);
                XO[m * 72 + cw + 16 + lm] = f2bf(acc2[ti][1][reg]);
            }
        __syncthreads();                       // OSB complete; KV reads done

        if (os >= 0) {
            uint4 v0 = *(const uint4*)&XO[om * 72 + oq * 16];
            uint4 v1 = *(const uint4*)&XO[om * 72 + oq * 16 + 8];
            unsigned short* op = Ob + (size_t)os * DDIM + cc * 64 + oq * 16;
            *(uint4*)op       = v0;
            *(uint4*)(op + 8) = v1;
        }
        if (cc < 15) stageV(cc + 1);
        __syncthreads();                       // drain async; OSB reads done
    }
}

// ---------------- Kernel R: out[n] = sum_j Ob[4n+j]  (bf16 -> fp32) ----------------
__global__ __launch_bounds__(256) void reduce_out(
    const unsigned short* __restrict__ Ob, float* __restrict__ out)
{
    const int tid = threadIdx.x;
    const int n   = blockIdx.x * 2 + (tid >> 7);
    const int cc  = (tid & 127) * 8;

    float s[8] = {};
    #pragma unroll
    for (int j = 0; j < 4; ++j) {
        uint4 v = *(const uint4*)&Ob[((size_t)n * 4 + j) * DDIM + cc];
        const unsigned int w[4] = {v.x, v.y, v.z, v.w};
        #pragma unroll
        for (int q = 0; q < 4; ++q) {
            s[q * 2 + 0] += bf2f((unsigned short)(w[q] & 0xffff));
            s[q * 2 + 1] += bf2f((unsigned short)(w[q] >> 16));
        }
    }
    float4 o0 = {s[0], s[1], s[2], s[3]};
    float4 o1 = {s[4], s[5], s[6], s[7]};
    *(float4*)&out[(size_t)n * DDIM + cc]     = o0;
    *(float4*)&out[(size_t)n * DDIM + cc + 4] = o1;
}

extern "C" void kernel_launch(void* const* d_in, const int* in_sizes, int n_in,
                              void* d_out, int out_size, void* d_ws, size_t ws_size,
                              hipStream_t stream) {
    const float* x      = (const float*)d_in[0];
    const float* es     = (const float*)d_in[1];
    const float* keys   = (const float*)d_in[2];
    const float* values = (const float*)d_in[3];
    float* out          = (float*)d_out;

    // workspace layout (~101 MB)
    char* w = (char*)d_ws;
    int*   cnt      = (int*)w;               w += 256;
    int*   tok_list = (int*)w;               w += (size_t)NEXP * NTOK * sizeof(int);    // 1 MB
    float* gates    = (float*)w;             w += (size_t)NTOK * TOPK * sizeof(float);  // 128 KB
    unsigned short* Kb = (unsigned short*)w; w += (size_t)NEXP * 128 * 128 * 8 * 2;     // 8 MB
    unsigned short* Vb = (unsigned short*)w; w += (size_t)NEXP * 16 * 1024 * 8 * 2;     // 8 MB
    unsigned short* Xb = (unsigned short*)w; w += (size_t)NTOK * DDIM * 2;              // 16.8 MB
    unsigned short* Ob = (unsigned short*)w;                                            // 67 MB

    hipMemsetAsync(cnt, 0, NEXP * sizeof(int), stream);

    prep_gate<<<512 + 4096, 256, 0, stream>>>(x, es, keys, values, Kb, Vb, Xb,
                                              cnt, tok_list, gates);
    ffn_fused<<<128 * NEXP, 256, 0, stream>>>(Xb, Kb, Vb, cnt, tok_list, gates, Ob);
    reduce_out<<<NTOK / 2, 256, 0, stream>>>(Ob, out);
}